// Round 1
// baseline (1622.818 us; speedup 1.0000x reference)
//
#include <hip/hip_runtime.h>
#include <math.h>

#define CCH 256
#define NBATCH 64
#define LLEN 4096
#define MTOT (NBATCH * LLEN)      // 262144
#define EPSV 1e-3f
#define NS_ITERS 7
#define GSPLIT 128
#define KSLICE (MTOT / GSPLIT)    // 2048 (within one n's row of 4096)

// ---------------- mean over [N, L] per channel ----------------
__global__ void mean_kernel(const float* __restrict__ X, float* __restrict__ mean) {
  const int c = blockIdx.x, t = threadIdx.x;
  float s = 0.f;
  for (int n = 0; n < NBATCH; ++n) {
    const float4* p = (const float4*)(X + (size_t)(n * CCH + c) * LLEN);
    for (int j = t; j < LLEN / 4; j += 256) {
      float4 v = p[j];
      s += (v.x + v.y) + (v.z + v.w);
    }
  }
  for (int off = 32; off > 0; off >>= 1) s += __shfl_down(s, off, 64);
  __shared__ float red[4];
  const int wave = t >> 6, lane = t & 63;
  if (lane == 0) red[wave] = s;
  __syncthreads();
  if (t == 0) mean[c] = (red[0] + red[1] + red[2] + red[3]) * (1.0f / MTOT);
}

// ---------------- Gram: G = x @ x^T  (split-K, atomics) ----------------
__global__ __launch_bounds__(256) void gram_kernel(const float* __restrict__ X,
                                                   float* __restrict__ G) {
  __shared__ float As[32][68];
  __shared__ float Bs[32][68];
  const int tid = threadIdx.x;
  const int tile = blockIdx.y;           // 0..15
  const int ca = (tile >> 2) * 64;
  const int cb = (tile & 3) * 64;
  const int k0 = blockIdx.x * KSLICE;
  const int n = k0 >> 12;
  const int l0 = k0 & 4095;
  const int lc = tid >> 2;               // 0..63 channel in tile
  const int lk = (tid & 3) * 8;          // 0,8,16,24
  const int ty = tid >> 4, tx = tid & 15;
  const int ci = ty * 4, cj = tx * 4;
  const float* Xn = X + (size_t)n * CCH * LLEN;
  float acc[4][4] = {{0.f}};
  for (int kc = 0; kc < KSLICE; kc += 32) {
    __syncthreads();
    const float* pa = Xn + (size_t)(ca + lc) * LLEN + l0 + kc + lk;
    float4 a0 = *(const float4*)pa;
    float4 a1 = *(const float4*)(pa + 4);
    const float* pb = Xn + (size_t)(cb + lc) * LLEN + l0 + kc + lk;
    float4 b0 = *(const float4*)pb;
    float4 b1 = *(const float4*)(pb + 4);
    As[lk + 0][lc] = a0.x; As[lk + 1][lc] = a0.y; As[lk + 2][lc] = a0.z; As[lk + 3][lc] = a0.w;
    As[lk + 4][lc] = a1.x; As[lk + 5][lc] = a1.y; As[lk + 6][lc] = a1.z; As[lk + 7][lc] = a1.w;
    Bs[lk + 0][lc] = b0.x; Bs[lk + 1][lc] = b0.y; Bs[lk + 2][lc] = b0.z; Bs[lk + 3][lc] = b0.w;
    Bs[lk + 4][lc] = b1.x; Bs[lk + 5][lc] = b1.y; Bs[lk + 6][lc] = b1.z; Bs[lk + 7][lc] = b1.w;
    __syncthreads();
#pragma unroll
    for (int k = 0; k < 32; ++k) {
      float4 a = *(const float4*)&As[k][ci];
      float4 b = *(const float4*)&Bs[k][cj];
      acc[0][0] += a.x * b.x; acc[0][1] += a.x * b.y; acc[0][2] += a.x * b.z; acc[0][3] += a.x * b.w;
      acc[1][0] += a.y * b.x; acc[1][1] += a.y * b.y; acc[1][2] += a.y * b.z; acc[1][3] += a.y * b.w;
      acc[2][0] += a.z * b.x; acc[2][1] += a.z * b.y; acc[2][2] += a.z * b.z; acc[2][3] += a.z * b.w;
      acc[3][0] += a.w * b.x; acc[3][1] += a.w * b.y; acc[3][2] += a.w * b.z; acc[3][3] += a.w * b.w;
    }
  }
#pragma unroll
  for (int r = 0; r < 4; ++r)
#pragma unroll
    for (int s = 0; s < 4; ++s)
      atomicAdd(&G[(size_t)(ca + ci + r) * CCH + (cb + cj + s)], acc[r][s]);
}

// ---------------- sigma = G/m - mean mean^T + eps I (in place), trace ----------------
__global__ void sigma_kernel(float* __restrict__ G, const float* __restrict__ mean,
                             float* __restrict__ trace) {
  const int idx = blockIdx.x * 256 + threadIdx.x;
  const int r = idx >> 8, cc = idx & 255;
  float v = G[idx] * (1.0f / MTOT) - mean[r] * mean[cc] + (r == cc ? EPSV : 0.f);
  G[idx] = v;
  if (r == cc) atomicAdd(trace, v);
}

// ---------------- Y0 = sigma/s, Z0 = I, rs = 1/sqrt(s) ----------------
__global__ void normalize_kernel(const float* __restrict__ SIG, const float* __restrict__ scal,
                                 float* __restrict__ Y, float* __restrict__ Z,
                                 float* __restrict__ rs) {
  const float s = scal[0] * (1.0f / CCH);
  const int idx = blockIdx.x * 256 + threadIdx.x;
  const int r = idx >> 8, cc = idx & 255;
  Y[idx] = SIG[idx] / s;
  Z[idx] = (r == cc) ? 1.0f : 0.0f;
  if (idx == 0) rs[0] = 1.0f / sqrtf(s);
}

// ---------------- generic 64x64-tile 256^3 matmul: C = alpha*A*B + beta*I ----------------
__device__ __forceinline__ void tile_mm64(const float* __restrict__ A,
                                          const float* __restrict__ B,
                                          float* __restrict__ Cm,
                                          int bi, int bj, float alpha, float beta) {
  __shared__ float As[32][68];
  __shared__ float Bs[32][68];
  const int tid = threadIdx.x;
  const int r0 = bi * 64, c0 = bj * 64;
  const int lc = tid >> 2;
  const int lk = (tid & 3) * 8;
  const int kx = tid >> 3;
  const int lx = (tid & 7) * 8;
  const int ty = tid >> 4, tx = tid & 15;
  const int ci = ty * 4, cj = tx * 4;
  float acc[4][4] = {{0.f}};
  for (int kc = 0; kc < CCH; kc += 32) {
    __syncthreads();
    const float* pa = A + (size_t)(r0 + lc) * CCH + kc + lk;
    float4 v0 = *(const float4*)pa;
    float4 v1 = *(const float4*)(pa + 4);
    As[lk + 0][lc] = v0.x; As[lk + 1][lc] = v0.y; As[lk + 2][lc] = v0.z; As[lk + 3][lc] = v0.w;
    As[lk + 4][lc] = v1.x; As[lk + 5][lc] = v1.y; As[lk + 6][lc] = v1.z; As[lk + 7][lc] = v1.w;
    const float* pb = B + (size_t)(kc + kx) * CCH + c0 + lx;
    *(float4*)&Bs[kx][lx]     = *(const float4*)pb;
    *(float4*)&Bs[kx][lx + 4] = *(const float4*)(pb + 4);
    __syncthreads();
#pragma unroll
    for (int k = 0; k < 32; ++k) {
      float4 a = *(const float4*)&As[k][ci];
      float4 b = *(const float4*)&Bs[k][cj];
      acc[0][0] += a.x * b.x; acc[0][1] += a.x * b.y; acc[0][2] += a.x * b.z; acc[0][3] += a.x * b.w;
      acc[1][0] += a.y * b.x; acc[1][1] += a.y * b.y; acc[1][2] += a.y * b.z; acc[1][3] += a.y * b.w;
      acc[2][0] += a.z * b.x; acc[2][1] += a.z * b.y; acc[2][2] += a.z * b.z; acc[2][3] += a.z * b.w;
      acc[3][0] += a.w * b.x; acc[3][1] += a.w * b.y; acc[3][2] += a.w * b.z; acc[3][3] += a.w * b.w;
    }
  }
#pragma unroll
  for (int r = 0; r < 4; ++r) {
    const int gr = r0 + ci + r;
#pragma unroll
    for (int s = 0; s < 4; ++s) {
      const int gc = c0 + cj + s;
      float v = alpha * acc[r][s];
      if (gr == gc) v += beta;
      Cm[(size_t)gr * CCH + gc] = v;
    }
  }
}

// T = 3I - Z*Y
__global__ __launch_bounds__(256) void nsT_kernel(const float* __restrict__ Z,
                                                  const float* __restrict__ Y,
                                                  float* __restrict__ T) {
  tile_mm64(Z, Y, T, blockIdx.x >> 2, blockIdx.x & 3, -1.0f, 3.0f);
}

// Yn = 0.5*Y*T   (blocks 0..15),  Zn = 0.5*T*Z  (blocks 16..31)
__global__ __launch_bounds__(256) void nsYZ_kernel(const float* __restrict__ Y,
                                                   const float* __restrict__ Z,
                                                   const float* __restrict__ T,
                                                   float* __restrict__ Yn,
                                                   float* __restrict__ Zn) {
  const int bid = blockIdx.x;
  const float* A; const float* B; float* Cm; int t;
  if (bid < 16) { A = Y; B = T; Cm = Yn; t = bid; }
  else          { A = T; B = Z; Cm = Zn; t = bid - 16; }
  tile_mm64(A, B, Cm, t >> 2, t & 3, 0.5f, 0.0f);
}

// WM = Z * (1/sqrt(s))
__global__ void scale_kernel(const float* __restrict__ Z, const float* __restrict__ rs,
                             float* __restrict__ WM) {
  const int idx = blockIdx.x * 256 + threadIdx.x;
  WM[idx] = Z[idx] * rs[0];
}

// bias[c] = sum_k WM[c,k] * mean[k]
__global__ void bias_kernel(const float* __restrict__ WM, const float* __restrict__ mean,
                            float* __restrict__ bias) {
  const int c = threadIdx.x;
  float s = 0.f;
  for (int k = 0; k < CCH; ++k) s += WM[(size_t)c * CCH + k] * mean[k];
  bias[c] = s;
}

// out[n,c,l] = sum_k WM[c,k] * X[n,k,l] - bias[c]
__global__ __launch_bounds__(256) void whiten_kernel(const float* __restrict__ X,
                                                     const float* __restrict__ WM,
                                                     const float* __restrict__ bias,
                                                     float* __restrict__ out) {
  __shared__ float Ws[32][68];
  __shared__ float Xs[32][68];
  const int tid = threadIdx.x;
  const int l0 = blockIdx.x * 64;
  const int c0 = blockIdx.y * 64;
  const int n  = blockIdx.z;
  const int lc = tid >> 2;
  const int lk = (tid & 3) * 8;
  const int kx = tid >> 3;
  const int lx = (tid & 7) * 8;
  const int ty = tid >> 4, tx = tid & 15;
  const int ci = ty * 4, lj = tx * 4;
  const float* Xn = X + (size_t)n * CCH * LLEN;
  float acc[4][4] = {{0.f}};
  for (int kc = 0; kc < CCH; kc += 32) {
    __syncthreads();
    const float* pw = WM + (size_t)(c0 + lc) * CCH + kc + lk;
    float4 w0 = *(const float4*)pw;
    float4 w1 = *(const float4*)(pw + 4);
    Ws[lk + 0][lc] = w0.x; Ws[lk + 1][lc] = w0.y; Ws[lk + 2][lc] = w0.z; Ws[lk + 3][lc] = w0.w;
    Ws[lk + 4][lc] = w1.x; Ws[lk + 5][lc] = w1.y; Ws[lk + 6][lc] = w1.z; Ws[lk + 7][lc] = w1.w;
    const float* px = Xn + (size_t)(kc + kx) * LLEN + l0 + lx;
    *(float4*)&Xs[kx][lx]     = *(const float4*)px;
    *(float4*)&Xs[kx][lx + 4] = *(const float4*)(px + 4);
    __syncthreads();
#pragma unroll
    for (int k = 0; k < 32; ++k) {
      float4 a = *(const float4*)&Ws[k][ci];
      float4 b = *(const float4*)&Xs[k][lj];
      acc[0][0] += a.x * b.x; acc[0][1] += a.x * b.y; acc[0][2] += a.x * b.z; acc[0][3] += a.x * b.w;
      acc[1][0] += a.y * b.x; acc[1][1] += a.y * b.y; acc[1][2] += a.y * b.z; acc[1][3] += a.y * b.w;
      acc[2][0] += a.z * b.x; acc[2][1] += a.z * b.y; acc[2][2] += a.z * b.z; acc[2][3] += a.z * b.w;
      acc[3][0] += a.w * b.x; acc[3][1] += a.w * b.y; acc[3][2] += a.w * b.z; acc[3][3] += a.w * b.w;
    }
  }
#pragma unroll
  for (int r = 0; r < 4; ++r) {
    const int c = c0 + ci + r;
    const float bv = bias[c];
    float4 o;
    o.x = acc[r][0] - bv; o.y = acc[r][1] - bv; o.z = acc[r][2] - bv; o.w = acc[r][3] - bv;
    *(float4*)(out + (size_t)n * CCH * LLEN + (size_t)c * LLEN + l0 + lj) = o;
  }
}

extern "C" void kernel_launch(void* const* d_in, const int* in_sizes, int n_in,
                              void* d_out, int out_size, void* d_ws, size_t ws_size,
                              hipStream_t stream) {
  const float* X = (const float*)d_in[0];
  float* out = (float*)d_out;
  float* ws = (float*)d_ws;
  const size_t MSZ = (size_t)CCH * CCH;   // 65536 floats

  float* G    = ws;                // sigma in place
  float* Y0   = ws + 1 * MSZ;
  float* Y1   = ws + 2 * MSZ;
  float* Z0   = ws + 3 * MSZ;
  float* Z1   = ws + 4 * MSZ;
  float* T    = ws + 5 * MSZ;
  float* WM   = ws + 6 * MSZ;
  float* mean = ws + 7 * MSZ;
  float* bias = mean + CCH;
  float* scal = bias + CCH;        // [0] = trace accum, [1] = 1/sqrt(s)

  hipMemsetAsync(G, 0, MSZ * sizeof(float), stream);
  hipMemsetAsync(scal, 0, 2 * sizeof(float), stream);

  mean_kernel<<<CCH, 256, 0, stream>>>(X, mean);
  gram_kernel<<<dim3(GSPLIT, 16), 256, 0, stream>>>(X, G);
  sigma_kernel<<<256, 256, 0, stream>>>(G, mean, scal);
  normalize_kernel<<<256, 256, 0, stream>>>(G, scal, Y0, Z0, scal + 1);

  float* Yc = Y0; float* Zc = Z0; float* Yn = Y1; float* Zn = Z1;
  for (int it = 0; it < NS_ITERS; ++it) {
    nsT_kernel<<<16, 256, 0, stream>>>(Zc, Yc, T);
    nsYZ_kernel<<<32, 256, 0, stream>>>(Yc, Zc, T, Yn, Zn);
    float* tmp;
    tmp = Yc; Yc = Yn; Yn = tmp;
    tmp = Zc; Zc = Zn; Zn = tmp;
  }

  scale_kernel<<<256, 256, 0, stream>>>(Zc, scal + 1, WM);
  bias_kernel<<<1, CCH, 0, stream>>>(WM, mean, bias);
  whiten_kernel<<<dim3(LLEN / 64, CCH / 64, NBATCH), 256, 0, stream>>>(X, WM, bias, out);
}